// Round 14
// baseline (20.633 us; speedup 1.0000x reference)
//
#include <hip/hip_runtime.h>
#include <hip/hip_fp16.h>
#include <math.h>

#define KNBR 20
#define BLK  256
#define GRP  16                 // lanes per atom (== one DPP row)
#define APB  (BLK / GRP)        // 16 atoms per block-tile
#define MAXP 190                // C(20,2)
#define PERSIST 2048            // 8 blocks/CU * 256 CU
#define GLUT 1024               // gaussian LUT intervals over d in [-1,1]

#define THETA_T  1.9106332362490186f   // 0.6081734479693927 * pi
#define INV_SIG  4.7746482927568605f   // 1 / (12 deg in rad)
#define PI_F     3.14159265358979323846f

// 16-lane row reduction via DPP row_ror adds — pure VALU pipe, zero LDS traffic.
#define DPPADD(v, ctrl) { \
    const int _t = __builtin_amdgcn_update_dpp(0, __float_as_int(v), ctrl, 0xF, 0xF, true); \
    v += __int_as_float(_t); }
#define RED16(v) { DPPADD(v, 0x121) DPPADD(v, 0x122) DPPADD(v, 0x124) DPPADD(v, 0x128) }

// Persistent blocks + 1-deep index prefetch (round-9 structure).
// q_l via SH addition theorem: q_l = (1/nb)*sqrt(cn + 2*sum_{i<j} P_l(d_ij)),
// P_l sums via moments m1=Σe, m2=Σe², m3=Σe³ (e = d²).
// Tet gaussian via 1025-entry LDS LUT + lerp.
// Unit vectors stored in LDS as half4 (8 B) — halves LDS-pipe cost per trip.
// Self-neighbors (vec=0): reference SH maps them to (1,0,0), tet keeps 0 —
// stored as (1,0,0,w=0); d_sh = dot3, d_tet = d_sh*A.w*B.w.
__global__ __launch_bounds__(BLK, 8)
void op_kernel(const float* __restrict__ pos,
               const int*   __restrict__ aidx,
               const int*   __restrict__ nidx,
               const int*   __restrict__ vmsk,
               float*       __restrict__ out,
               int M, int NT)
{
    __shared__ uint2 su[APB * KNBR];        // 2560 B (half4 per slot)
    __shared__ unsigned short lut[MAXP];    // 380 B: ii | (j<<8)
    __shared__ float glut[GLUT + 1];        // 4100 B: gauss(acos(d)) table

    const int tid = threadIdx.x;
    if (tid < MAXP) {
        const int j = (int)((1.0f + sqrtf(fmaf(8.f, (float)tid, 1.0f))) * 0.5f);
        lut[tid] = (unsigned short)((tid - ((j * (j - 1)) >> 1)) | (j << 8));
    }
    for (int k = tid; k <= GLUT; k += BLK) {
        const float d  = fmaf((float)k, 2.0f / GLUT, -1.0f);
        const float dc = fminf(fmaxf(d, -0.9999999f), 0.9999999f);
        const float ad = fabsf(dc);
        const float pq = fmaf(fmaf(fmaf(-0.0187293f, ad, 0.0742610f), ad,
                              -0.2121144f), ad, 1.5707288f) * sqrtf(1.f - ad);
        const float ang = (dc >= 0.f) ? pq : PI_F - pq;
        const float tt = (ang - THETA_T) * INV_SIG;
        glut[k] = __expf(-0.5f * tt * tt);
    }
    __syncthreads();

    const int r   = tid & (GRP - 1);        // lane within 16-lane group (DPP row)
    const int g   = tid / GRP;              // group in block 0..15
    const int sub = (tid & 63) >> 4;        // 16-lane subgroup within wave
    uint2* row = &su[g * KNBR];

    int t = blockIdx.x;
    if (t >= NT) return;

    // ---- stage tile t ----
    int i = t * APB + g;
    int is = min(i, M - 1);
    int a  = aidx[is];
    size_t ri = (size_t)is * KNBR;
    int n0 = nidx[ri + r];
    int v0 = (i < M) ? vmsk[ri + r] : 0;
    int n1 = 0, v1 = 0;
    if (r < 4) { n1 = nidx[ri + 16 + r]; v1 = (i < M) ? vmsk[ri + 16 + r] : 0; }

    while (true) {
        const int tn = t + gridDim.x;
        // ---- prefetch tile tn's indices (hides HBM latency under compute) ----
        int aN = 0, n0N = 0, v0N = 0, n1N = 0, v1N = 0, iN = 0;
        if (tn < NT) {
            iN = tn * APB + g;
            const int isN = min(iN, M - 1);
            aN = aidx[isN];
            const size_t rN = (size_t)isN * KNBR;
            n0N = nidx[rN + r];
            v0N = (iN < M) ? vmsk[rN + r] : 0;
            if (r < 4) { n1N = nidx[rN + 16 + r]; v1N = (iN < M) ? vmsk[rN + 16 + r] : 0; }
        }

        // ---- compute tile t ----
        const int use1 = (r < 4) & (v1 != 0);
        const int s0i = (v0 != 0) ? n0 : 0;
        const int s1i = use1 ? n1 : 0;
        const float cx = pos[3*a], cy = pos[3*a+1], cz = pos[3*a+2];
        const float p0x = pos[3*s0i], p0y = pos[3*s0i+1], p0z = pos[3*s0i+2];
        const float p1x = pos[3*s1i], p1y = pos[3*s1i+1], p1z = pos[3*s1i+2];

        const unsigned long long bal0 = __ballot(v0 != 0);
        const unsigned long long bal1 = __ballot(use1 != 0);
        const unsigned int b16 = (unsigned int)(bal0 >> (sub * 16)) & 0xFFFFu;
        const unsigned int c4  = (unsigned int)(bal1 >> (sub * 16)) & 0xFu;
        const unsigned int mask20 = b16 | (c4 << 16);
        const int total = __popc(mask20);

        if (v0 != 0) {
            const float vx = p0x - cx, vy = p0y - cy, vz = p0z - cz;
            const float d2 = fmaf(vx, vx, fmaf(vy, vy, vz * vz));
            const int   zed = d2 < 1e-24f;
            const float inv = __builtin_amdgcn_rcpf(sqrtf(d2) + 1e-10f);
            const int slot = __popc(mask20 & ((1u << r) - 1u));
            const __half2 h01 = __floats2half2_rn(zed ? 1.f : vx * inv,
                                                  zed ? 0.f : vy * inv);
            const __half2 h23 = __floats2half2_rn(zed ? 0.f : vz * inv,
                                                  zed ? 0.f : 1.f);
            uint2 pk;
            pk.x = *reinterpret_cast<const unsigned*>(&h01);
            pk.y = *reinterpret_cast<const unsigned*>(&h23);
            row[slot] = pk;
        }
        if (use1) {
            const float vx = p1x - cx, vy = p1y - cy, vz = p1z - cz;
            const float d2 = fmaf(vx, vx, fmaf(vy, vy, vz * vz));
            const int   zed = d2 < 1e-24f;
            const float inv = __builtin_amdgcn_rcpf(sqrtf(d2) + 1e-10f);
            const int slot = __popc(mask20 & ((1u << (16 + r)) - 1u));
            const __half2 h01 = __floats2half2_rn(zed ? 1.f : vx * inv,
                                                  zed ? 0.f : vy * inv);
            const __half2 h23 = __floats2half2_rn(zed ? 0.f : vz * inv,
                                                  zed ? 0.f : 1.f);
            uint2 pk;
            pk.x = *reinterpret_cast<const unsigned*>(&h01);
            pk.y = *reinterpret_cast<const unsigned*>(&h23);
            row[slot] = pk;
        }
        // writers == readers (same wave): DS program order, no barrier needed.

        const int npairs = (total * (total - 1)) >> 1;
        float m1 = 0.f, m2 = 0.f, m3 = 0.f, gsum = 0.f;
        for (int p = r; p < npairs; p += GRP) {
            const unsigned short pw = lut[p];
            const uint2 A2 = row[pw & 0xFF];
            const uint2 B2 = row[pw >> 8];
            const float2 fa01 = __half22float2(*reinterpret_cast<const __half2*>(&A2.x));
            const float2 fa23 = __half22float2(*reinterpret_cast<const __half2*>(&A2.y));
            const float2 fb01 = __half22float2(*reinterpret_cast<const __half2*>(&B2.x));
            const float2 fb23 = __half22float2(*reinterpret_cast<const __half2*>(&B2.y));

            const float dsh = fmaf(fa01.x, fb01.x,
                             fmaf(fa01.y, fb01.y, fa23.x * fb23.x));
            const float dtt = dsh * fa23.y * fb23.y;

            const float e  = dsh * dsh;
            const float e2 = e * e;
            m1 += e;
            m2 += e2;
            m3 = fmaf(e2, e, m3);

            // gaussian via LUT + lerp (replaces acos poly + exp)
            float fx = fmaf(dtt, (float)(GLUT / 2), (float)(GLUT / 2));
            fx = fminf(fmaxf(fx, 0.f), (float)GLUT - 0.0001f);
            const int   k  = (int)fx;
            const float fr = fx - (float)k;
            const float g0 = glut[k];
            const float g1 = glut[k + 1];
            gsum += fmaf(fr, g1 - g0, g0);
        }

        RED16(m1) RED16(m2) RED16(m3) RED16(gsum)

        const float fnp = (float)npairs;
        const float s2 = fmaf(1.5f, m1, -0.5f * fnp);
        const float s4 = fmaf(4.375f, m2, fmaf(-3.75f, m1, 0.375f * fnp));
        const float s6 = fmaf(14.4375f, m3,
                         fmaf(-19.6875f, m2, fmaf(6.5625f, m1, -0.3125f * fnp)));

        const float cn = (float)total;
        const float invnb = 1.f / fmaxf(cn, 1.f);
        const float tet = 2.f * gsum / fmaxf(cn * (cn - 1.f), 1.f);
        const float q2v = invnb * sqrtf(fmaxf(fmaf(2.f, s2, cn), 0.f));
        const float q4v = invnb * sqrtf(fmaxf(fmaf(2.f, s4, cn), 0.f));
        const float q6v = invnb * sqrtf(fmaxf(fmaf(2.f, s6, cn), 0.f));

        float val = cn;
        val = (r == 1) ? tet : val;
        val = (r == 2) ? q2v : val;
        val = (r == 3) ? q4v : val;
        val = (r == 4) ? q6v : val;
        if (r < 5 && i < M)
            out[r * M + i] = val;

        if (tn >= NT) break;
        t = tn; i = iN; a = aN;
        n0 = n0N; v0 = v0N; n1 = n1N; v1 = v1N;
    }
}

extern "C" void kernel_launch(void* const* d_in, const int* in_sizes, int n_in,
                              void* d_out, int out_size, void* d_ws, size_t ws_size,
                              hipStream_t stream) {
    const float* pos  = (const float*)d_in[0];
    const int*   aidx = (const int*)d_in[1];
    const int*   nidx = (const int*)d_in[2];
    const int*   vmsk = (const int*)d_in[3];
    float* out = (float*)d_out;
    const int M = in_sizes[1];
    const int NT = (M + APB - 1) / APB;
    const int grid = NT < PERSIST ? NT : PERSIST;
    op_kernel<<<grid, BLK, 0, stream>>>(pos, aidx, nidx, vmsk, out, M, NT);
}

// Round 15
// 19.580 us; speedup vs baseline: 1.0538x; 1.0538x over previous
//
#include <hip/hip_runtime.h>
#include <math.h>

#define KNBR 20
#define BLK  256
#define GRP  16                 // lanes per atom
#define APB  (BLK / GRP)        // 16 atoms per block-tile
#define MAXP 190                // C(20,2)
#define PERSIST 2048            // 8 blocks/CU * 256 CU
#define GLUT 1024               // gaussian LUT intervals over d in [-1,1]

#define THETA_T  1.9106332362490186f   // 0.6081734479693927 * pi
#define INV_SIG  4.7746482927568605f   // 1 / (12 deg in rad)
#define PI_F     3.14159265358979323846f

// Persistent blocks + 1-deep index prefetch (round-9 winner structure).
// q_l via SH addition theorem: q_l = (1/nb)*sqrt(cn + 2*sum_{i<j} P_l(d_ij)),
// P_l sums via moments m1=Σe, m2=Σe², m3=Σe³ (e = d²).
// Tet gaussian via 1025-entry LDS LUT + lerp (g(d) is smooth; ~1e-5 interp err).
// Self-neighbors (vec=0): reference SH maps them to (1,0,0), tet keeps 0 —
// stored as (1,0,0,w=0); d_sh = dot3, d_tet = d_sh*A.w*B.w.
//
// R15 change vs R13: __launch_bounds__ min-waves/EU 8 -> 4 (VGPR cap 64 -> 128).
// A/B test for the scratch-spill hypothesis: R8-R14 all capped at 64 VGPR while
// round 1's SIMPLER kernel measured 68 VGPR uncapped — the cap likely forces
// pair-loop spills, which would explain the ~20us wall's insensitivity to every
// pipe-level optimization.
__global__ __launch_bounds__(BLK, 4)
void op_kernel(const float* __restrict__ pos,
               const int*   __restrict__ aidx,
               const int*   __restrict__ nidx,
               const int*   __restrict__ vmsk,
               float*       __restrict__ out,
               int M, int NT)
{
    __shared__ float4 su[APB * KNBR];       // 5120 B
    __shared__ unsigned short lut[MAXP];    // 380 B: ii | (j<<8)
    __shared__ float glut[GLUT + 1];        // 4100 B: gauss(acos(d)) table

    const int tid = threadIdx.x;
    if (tid < MAXP) {
        const int j = (int)((1.0f + sqrtf(fmaf(8.f, (float)tid, 1.0f))) * 0.5f);
        lut[tid] = (unsigned short)((tid - ((j * (j - 1)) >> 1)) | (j << 8));
    }
    for (int k = tid; k <= GLUT; k += BLK) {
        const float d  = fmaf((float)k, 2.0f / GLUT, -1.0f);
        const float dc = fminf(fmaxf(d, -0.9999999f), 0.9999999f);
        const float ad = fabsf(dc);
        const float pq = fmaf(fmaf(fmaf(-0.0187293f, ad, 0.0742610f), ad,
                              -0.2121144f), ad, 1.5707288f) * sqrtf(1.f - ad);
        const float ang = (dc >= 0.f) ? pq : PI_F - pq;
        const float tt = (ang - THETA_T) * INV_SIG;
        glut[k] = __expf(-0.5f * tt * tt);
    }
    __syncthreads();

    const int r   = tid & (GRP - 1);        // lane within 16-lane group
    const int g   = tid / GRP;              // group in block 0..15
    const int sub = (tid & 63) >> 4;        // 16-lane subgroup within wave
    float4* row = &su[g * KNBR];

    int t = blockIdx.x;
    if (t >= NT) return;

    // ---- stage tile t ----
    int i = t * APB + g;
    int is = min(i, M - 1);
    int a  = aidx[is];
    size_t ri = (size_t)is * KNBR;
    int n0 = nidx[ri + r];
    int v0 = (i < M) ? vmsk[ri + r] : 0;
    int n1 = 0, v1 = 0;
    if (r < 4) { n1 = nidx[ri + 16 + r]; v1 = (i < M) ? vmsk[ri + 16 + r] : 0; }

    while (true) {
        const int tn = t + gridDim.x;
        // ---- prefetch tile tn's indices (hides HBM latency under compute) ----
        int aN = 0, n0N = 0, v0N = 0, n1N = 0, v1N = 0, iN = 0;
        if (tn < NT) {
            iN = tn * APB + g;
            const int isN = min(iN, M - 1);
            aN = aidx[isN];
            const size_t rN = (size_t)isN * KNBR;
            n0N = nidx[rN + r];
            v0N = (iN < M) ? vmsk[rN + r] : 0;
            if (r < 4) { n1N = nidx[rN + 16 + r]; v1N = (iN < M) ? vmsk[rN + 16 + r] : 0; }
        }

        // ---- compute tile t ----
        const int use1 = (r < 4) & (v1 != 0);
        const int s0i = (v0 != 0) ? n0 : 0;
        const int s1i = use1 ? n1 : 0;
        const float cx = pos[3*a], cy = pos[3*a+1], cz = pos[3*a+2];
        const float p0x = pos[3*s0i], p0y = pos[3*s0i+1], p0z = pos[3*s0i+2];
        const float p1x = pos[3*s1i], p1y = pos[3*s1i+1], p1z = pos[3*s1i+2];

        const unsigned long long bal0 = __ballot(v0 != 0);
        const unsigned long long bal1 = __ballot(use1 != 0);
        const unsigned int b16 = (unsigned int)(bal0 >> (sub * 16)) & 0xFFFFu;
        const unsigned int c4  = (unsigned int)(bal1 >> (sub * 16)) & 0xFu;
        const unsigned int mask20 = b16 | (c4 << 16);
        const int total = __popc(mask20);

        if (v0 != 0) {
            const float vx = p0x - cx, vy = p0y - cy, vz = p0z - cz;
            const float d2 = fmaf(vx, vx, fmaf(vy, vy, vz * vz));
            const int   zed = d2 < 1e-24f;
            const float inv = __builtin_amdgcn_rcpf(sqrtf(d2) + 1e-10f);
            const int slot = __popc(mask20 & ((1u << r) - 1u));
            row[slot] = make_float4(zed ? 1.f : vx * inv,
                                    zed ? 0.f : vy * inv,
                                    zed ? 0.f : vz * inv,
                                    zed ? 0.f : 1.f);
        }
        if (use1) {
            const float vx = p1x - cx, vy = p1y - cy, vz = p1z - cz;
            const float d2 = fmaf(vx, vx, fmaf(vy, vy, vz * vz));
            const int   zed = d2 < 1e-24f;
            const float inv = __builtin_amdgcn_rcpf(sqrtf(d2) + 1e-10f);
            const int slot = __popc(mask20 & ((1u << (16 + r)) - 1u));
            row[slot] = make_float4(zed ? 1.f : vx * inv,
                                    zed ? 0.f : vy * inv,
                                    zed ? 0.f : vz * inv,
                                    zed ? 0.f : 1.f);
        }
        // writers == readers (same wave): DS program order, no barrier needed.

        const int npairs = (total * (total - 1)) >> 1;
        float m1 = 0.f, m2 = 0.f, m3 = 0.f, gsum = 0.f;
        for (int p = r; p < npairs; p += GRP) {
            const unsigned short w = lut[p];
            const float4 A = row[w & 0xFF];
            const float4 B = row[w >> 8];
            const float dsh = fmaf(A.x, B.x, fmaf(A.y, B.y, A.z * B.z));
            const float dtt = dsh * A.w * B.w;

            const float e  = dsh * dsh;
            const float e2 = e * e;
            m1 += e;
            m2 += e2;
            m3 = fmaf(e2, e, m3);

            // gaussian via LUT + lerp (replaces acos poly + exp)
            float fx = fmaf(dtt, (float)(GLUT / 2), (float)(GLUT / 2));
            fx = fminf(fmaxf(fx, 0.f), (float)GLUT - 0.0001f);
            const int   k  = (int)fx;
            const float fr = fx - (float)k;
            const float g0 = glut[k];
            const float g1 = glut[k + 1];
            gsum += fmaf(fr, g1 - g0, g0);
        }

#define RED(v) { v += __shfl_xor(v,1); v += __shfl_xor(v,2); \
                 v += __shfl_xor(v,4); v += __shfl_xor(v,8); }
        RED(m1) RED(m2) RED(m3) RED(gsum)
#undef RED

        const float fnp = (float)npairs;
        const float s2 = fmaf(1.5f, m1, -0.5f * fnp);
        const float s4 = fmaf(4.375f, m2, fmaf(-3.75f, m1, 0.375f * fnp));
        const float s6 = fmaf(14.4375f, m3,
                         fmaf(-19.6875f, m2, fmaf(6.5625f, m1, -0.3125f * fnp)));

        const float cn = (float)total;
        const float invnb = 1.f / fmaxf(cn, 1.f);
        const float tet = 2.f * gsum / fmaxf(cn * (cn - 1.f), 1.f);
        const float q2v = invnb * sqrtf(fmaxf(fmaf(2.f, s2, cn), 0.f));
        const float q4v = invnb * sqrtf(fmaxf(fmaf(2.f, s4, cn), 0.f));
        const float q6v = invnb * sqrtf(fmaxf(fmaf(2.f, s6, cn), 0.f));

        float val = cn;
        val = (r == 1) ? tet : val;
        val = (r == 2) ? q2v : val;
        val = (r == 3) ? q4v : val;
        val = (r == 4) ? q6v : val;
        if (r < 5 && i < M)
            out[r * M + i] = val;

        if (tn >= NT) break;
        t = tn; i = iN; a = aN;
        n0 = n0N; v0 = v0N; n1 = n1N; v1 = v1N;
    }
}

extern "C" void kernel_launch(void* const* d_in, const int* in_sizes, int n_in,
                              void* d_out, int out_size, void* d_ws, size_t ws_size,
                              hipStream_t stream) {
    const float* pos  = (const float*)d_in[0];
    const int*   aidx = (const int*)d_in[1];
    const int*   nidx = (const int*)d_in[2];
    const int*   vmsk = (const int*)d_in[3];
    float* out = (float*)d_out;
    const int M = in_sizes[1];
    const int NT = (M + APB - 1) / APB;
    const int grid = NT < PERSIST ? NT : PERSIST;
    op_kernel<<<grid, BLK, 0, stream>>>(pos, aidx, nidx, vmsk, out, M, NT);
}